// Round 8
// baseline (484.674 us; speedup 1.0000x reference)
//
#include <hip/hip_runtime.h>
#include <math.h>

#define S_DIM 1024
#define B_DIM 4
#define E_DIM 1024
#define H_DIM 16
#define M_DIM 128
#define V_DIM 64

typedef __attribute__((ext_vector_type(8))) short short8;
typedef __attribute__((ext_vector_type(4))) float f32x4;
typedef __attribute__((ext_vector_type(4))) int int4v;

__device__ __forceinline__ unsigned short f2bf(float f) {
    union { float f; unsigned u; } v; v.f = f;
    unsigned r = v.u + 0x7FFFu + ((v.u >> 16) & 1u);   // round-to-nearest-even
    return (unsigned short)(r >> 16);
}

__device__ __forceinline__ void async16(const unsigned short* g, unsigned short* l) {
    __builtin_amdgcn_global_load_lds(
        (const __attribute__((address_space(1))) void*)g,
        (__attribute__((address_space(3))) void*)l,
        16, 0, 0);
}

// ---------------- convert: fp32 (re,im) -> bf16, all 4 tensors in one launch ----------------
// segments (in float4 units): x 1048576 | wq 524288 | wk 524288 | wv 262144
__global__ __launch_bounds__(256) void convert_all(
    const float* __restrict__ xre,  const float* __restrict__ xim,
    const float* __restrict__ wqre, const float* __restrict__ wqim,
    const float* __restrict__ wkre, const float* __restrict__ wkim,
    const float* __restrict__ wvre, const float* __restrict__ wvim,
    unsigned short* __restrict__ xbre, unsigned short* __restrict__ xbim,
    unsigned short* __restrict__ wbre, unsigned short* __restrict__ wbim)
{
    const int i = blockIdx.x * 256 + threadIdx.x;
    const float *re, *im;
    unsigned short *dr, *di;
    int j;
    if (i < 1048576)      { re = xre;  im = xim;  dr = xbre;               di = xbim;               j = i; }
    else if (i < 1572864) { re = wqre; im = wqim; dr = wbre;               di = wbim;               j = i - 1048576; }
    else if (i < 2097152) { re = wkre; im = wkim; dr = wbre + 2048 * 1024; di = wbim + 2048 * 1024; j = i - 1572864; }
    else                  { re = wvre; im = wvim; dr = wbre + 4096 * 1024; di = wbim + 4096 * 1024; j = i - 2097152; }
    float4 r = ((const float4*)re)[j];
    float4 m = ((const float4*)im)[j];
    ushort4 ro, mo;
    ro.x = f2bf(r.x); ro.y = f2bf(r.y); ro.z = f2bf(r.z); ro.w = f2bf(r.w);
    mo.x = f2bf(m.x); mo.y = f2bf(m.y); mo.z = f2bf(m.z); mo.w = f2bf(m.w);
    ((ushort4*)dr)[j] = ro;
    ((ushort4*)di)[j] = mo;
}

// wo (e,f) -> woT (f,e) bf16
__global__ __launch_bounds__(256) void transpose_wo(
    const float* __restrict__ wore, const float* __restrict__ woim,
    unsigned short* __restrict__ wtre, unsigned short* __restrict__ wtim)
{
    __shared__ float tr[32][33], ti[32][33];
    const int bx = blockIdx.x * 32;   // e range
    const int by = blockIdx.y * 32;   // f range
    const int tx = threadIdx.x & 31, ty = threadIdx.x >> 5;
    for (int i = ty; i < 32; i += 8) {
        tr[i][tx] = wore[(bx + i) * E_DIM + by + tx];
        ti[i][tx] = woim[(bx + i) * E_DIM + by + tx];
    }
    __syncthreads();
    for (int i = ty; i < 32; i += 8) {
        wtre[(by + i) * E_DIM + bx + tx] = f2bf(tr[tx][i]);
        wtim[(by + i) * E_DIM + bx + tx] = f2bf(ti[tx][i]);
    }
}

// v planes [bh][t][64] -> v^T planes [bh][v][1024]
__global__ __launch_bounds__(256) void vtrans(
    const unsigned short* __restrict__ vrp, const unsigned short* __restrict__ vip,
    unsigned short* __restrict__ vrt, unsigned short* __restrict__ vit)
{
    __shared__ unsigned short tl[2][64][66];
    const int tid = threadIdx.x;
    const int t0 = blockIdx.x * 64;
    const int bh = blockIdx.y;
    #pragma unroll
    for (int pl = 0; pl < 2; ++pl) {
        const unsigned short* src = pl ? vip : vrp;
        #pragma unroll
        for (int p = 0; p < 2; ++p) {
            const int row = p * 32 + (tid >> 3);
            const int col = (tid & 7) * 8;
            short8 d = *(const short8*)&src[((size_t)bh * S_DIM + t0 + row) * V_DIM + col];
            #pragma unroll
            for (int j = 0; j < 8; ++j) tl[pl][row][col + j] = (unsigned short)d[j];
        }
    }
    __syncthreads();
    #pragma unroll
    for (int pl = 0; pl < 2; ++pl) {
        unsigned short* dst = pl ? vit : vrt;
        #pragma unroll
        for (int p = 0; p < 2; ++p) {
            const int v = p * 32 + (tid >> 3);
            const int tc = (tid & 7) * 8;
            short8 d;
            #pragma unroll
            for (int j = 0; j < 8; ++j) d[j] = (short)tl[pl][tc + j][v];
            *(short8*)&dst[((size_t)bh * V_DIM + v) * S_DIM + t0 + tc] = d;
        }
    }
}

// ---------------- complex bf16 MFMA GEMM: C = A * B^T ----------------
// MODE 0 (frozen since round 5: 154 us, MfmaUtil 52%, 0 bank conflicts):
// block 128x128, 4 waves (2x2), wave tile 64x64, 16x16x32 frags, BK=32,
// T3-min double-buffer, chunk-XOR swizzle. qscale folded into q epilogue.
// MODE 1 (round-8 fix): the 128x128 tile gave only 256 blocks = 1 block/CU =
// 1 wave/SIMD -> the vmcnt(0) drain had no co-resident block to hide under.
// BM=64 tile (wave tile 32x64, 48 KB LDS, 3 blocks/CU) -> 512 blocks ->
// cross-block overlap restored. Same verified swizzle/read/epilogue patterns
// (all row-offset-invariant).
template<int MODE>
__global__ __launch_bounds__(256, MODE ? 3 : 2) void cgemm(
    const unsigned short* __restrict__ Are, const unsigned short* __restrict__ Aim,
    const unsigned short* __restrict__ Bre, const unsigned short* __restrict__ Bim,
    unsigned short* __restrict__ qrp, unsigned short* __restrict__ qip,
    unsigned short* __restrict__ krp, unsigned short* __restrict__ kip,
    unsigned short* __restrict__ vrp, unsigned short* __restrict__ vip,
    const float* __restrict__ xre, const float* __restrict__ xim,
    float* __restrict__ out)
{
    constexpr int BM  = MODE ? 64 : 128;       // block M rows
    constexpr int IM  = MODE ? 2 : 4;          // wave m-frag count
    constexpr int ASZ = BM * 32;               // A plane elems per slice buffer
    constexpr int BUF = 2 * ASZ + 8192;        // elems per slice buffer (A*2 + B*2)
    __shared__ __align__(16) unsigned short lds[2 * BUF];
    const int tid  = threadIdx.x;
    const int wave = tid >> 6;
    const int lane = tid & 63;
    const int r0 = blockIdx.x * BM;
    const int j0 = blockIdx.y * 128;
    const int wm = (wave >> 1) * (MODE ? 32 : 64);   // m part
    const int wn = (wave & 1) * 64;                  // n half

    f32x4 accre[IM][4], accim[IM][4];
    #pragma unroll
    for (int i = 0; i < IM; ++i)
        #pragma unroll
        for (int j = 0; j < 4; ++j) {
            accre[i][j] = (f32x4){0.f, 0.f, 0.f, 0.f};
            accim[i][j] = (f32x4){0.f, 0.f, 0.f, 0.f};
        }

    const int sr   = tid >> 2;
    const int sc   = (tid & 3) * 8;                          // physical chunk (shorts)
    const int scol = ((tid & 3) ^ ((tid >> 3) & 3)) * 8;     // pre-swizzled source col

    const int fr = lane & 15;                                // frag m/n index
    const int xc = ((lane >> 4) ^ ((lane >> 1) & 3)) * 8;    // swizzled k-chunk on read

    #define STAGE(sl, bb) { \
        const int kg = (sl) * 32; \
        unsigned short* b_ = &lds[(bb) * BUF]; \
        const size_t ga0 = (size_t)(r0 + sr) * E_DIM + kg + scol; \
        const size_t gb0 = (size_t)(j0 + sr) * E_DIM + kg + scol; \
        const size_t gb1 = (size_t)(j0 + 64 + sr) * E_DIM + kg + scol; \
        async16(Are + ga0, b_ + sr * 32 + sc); \
        async16(Aim + ga0, b_ + ASZ + sr * 32 + sc); \
        if (MODE == 0) { \
            const size_t ga1 = (size_t)(r0 + 64 + sr) * E_DIM + kg + scol; \
            async16(Are + ga1, b_ + (64 + sr) * 32 + sc); \
            async16(Aim + ga1, b_ + ASZ + (64 + sr) * 32 + sc); \
        } \
        async16(Bre + gb0, b_ + 2 * ASZ + sr * 32 + sc); \
        async16(Bre + gb1, b_ + 2 * ASZ + (64 + sr) * 32 + sc); \
        async16(Bim + gb0, b_ + 2 * ASZ + 4096 + sr * 32 + sc); \
        async16(Bim + gb1, b_ + 2 * ASZ + 4096 + (64 + sr) * 32 + sc); }

    STAGE(0, 0)
    asm volatile("s_waitcnt vmcnt(0)" ::: "memory");
    __builtin_amdgcn_s_barrier();

    #pragma unroll 1
    for (int s = 0; s < 32; ++s) {
        if (s < 31) STAGE(s + 1, (s + 1) & 1)

        const unsigned short* buf = &lds[(s & 1) * BUF];
        short8 ar[IM], ai[IM];
        #pragma unroll
        for (int im = 0; im < IM; ++im) {
            const int ro = (wm + im * 16 + fr) * 32 + xc;
            ar[im] = *(const short8*)&buf[ro];
            ai[im] = *(const short8*)&buf[ASZ + ro];
        }
        #pragma unroll
        for (int jn = 0; jn < 4; ++jn) {
            const int ro = (wn + jn * 16 + fr) * 32 + xc;
            const short8 br = *(const short8*)&buf[2 * ASZ + ro];
            const short8 bi = *(const short8*)&buf[2 * ASZ + 4096 + ro];
            int4v t = *(int4v*)&bi;
            t = t ^ (int)0x80008000;       // bin = -bi (transient)
            const short8 bin = *(short8*)&t;
            #pragma unroll
            for (int im = 0; im < IM; ++im) {
                accre[im][jn] = __builtin_amdgcn_mfma_f32_16x16x32_bf16(ar[im], br,  accre[im][jn], 0, 0, 0);
                accre[im][jn] = __builtin_amdgcn_mfma_f32_16x16x32_bf16(ai[im], bin, accre[im][jn], 0, 0, 0);
                accim[im][jn] = __builtin_amdgcn_mfma_f32_16x16x32_bf16(ar[im], bi,  accim[im][jn], 0, 0, 0);
                accim[im][jn] = __builtin_amdgcn_mfma_f32_16x16x32_bf16(ai[im], br,  accim[im][jn], 0, 0, 0);
            }
        }

        if (s < 31) {
            asm volatile("s_waitcnt vmcnt(0)" ::: "memory");
            __builtin_amdgcn_s_barrier();
        }
    }
    #undef STAGE

    // epilogue: D row = (lane>>4)*4+reg, col = lane&15  [measured m89/m91]
    const float qscale = 0.088388347648318447f;  // 1/sqrt(128), folded into q planes
    #pragma unroll
    for (int im = 0; im < IM; ++im) {
        #pragma unroll
        for (int reg = 0; reg < 4; ++reg) {
            const int r = r0 + wm + im * 16 + (lane >> 4) * 4 + reg;
            #pragma unroll
            for (int jn = 0; jn < 4; ++jn) {
                const int j = j0 + wn + jn * 16 + fr;
                const float vr = accre[im][jn][reg];
                const float vi = accim[im][jn][reg];
                if (MODE == 0) {
                    const int s = r >> 2, b = r & 3;   // r = s*B + b
                    if (j < 2048) {
                        const int h = j >> 7, m = j & 127;
                        const size_t off = ((size_t)(b * H_DIM + h) * S_DIM + s) * M_DIM + m;
                        qrp[off] = f2bf(vr * qscale); qip[off] = f2bf(vi * qscale);
                    } else if (j < 4096) {
                        const int jl = j - 2048, h = jl >> 7, m = jl & 127;
                        const size_t off = ((size_t)(b * H_DIM + h) * S_DIM + s) * M_DIM + m;
                        krp[off] = f2bf(vr); kip[off] = f2bf(vi);
                    } else {
                        const int jl = j - 4096, h = jl >> 6, vv = jl & 63;
                        const size_t off = ((size_t)(b * H_DIM + h) * S_DIM + s) * V_DIM + vv;
                        vrp[off] = f2bf(vr); vip[off] = f2bf(vi);
                    }
                } else {
                    const int idx = r * E_DIM + j;
                    out[idx] = vr + xre[idx];
                    out[S_DIM * B_DIM * E_DIM + idx] = vi + xim[idx];
                }
            }
        }
    }
}

// ---------------- K2: MFMA flash attention, S^T orientation, QBLK=128 ----------------
// Round-8: 8 waves (512 threads) per block, 128 q rows. K/V tile staged ONCE
// per 128 q (vs per 64) -> staging traffic and barrier count x0.53; per-wave
// register layout unchanged (each wave owns 16 q). Q frags load directly from
// global (one-shot). LDS 75.8 KB -> 2 blocks/CU = 16 waves/CU under
// __launch_bounds__(512,4). Wave-uniform guard skips the final fully-masked
// tile for waves 0-3 (barriers stay unconditional -> no deadlock).
// XCD remap: 512 blocks all co-resident; n%8 ~ XCD -> bh = (n&7)+8*(n>>6)
// gives each XCD 8 bh whose 8 qt-blocks run concurrently (temporal K/V reuse).
// Kept: folded qscale, T13 defer-max, packed ushort4 Ps (pitch 88), setprio.
__global__ __launch_bounds__(512, 4) void attn_mfma(
    const unsigned short* __restrict__ qr, const unsigned short* __restrict__ qi,
    const unsigned short* __restrict__ kr, const unsigned short* __restrict__ ki,
    const unsigned short* __restrict__ vrt, const unsigned short* __restrict__ vit,
    unsigned short* __restrict__ updre, unsigned short* __restrict__ updim)
{
    __shared__ __align__(16) unsigned short Ks[2][64][136];  // K tile [plane][t][m]
    __shared__ __align__(16) unsigned short Vs[2][64][72];   // V^T tile [plane][v][t]
    __shared__ __align__(16) unsigned short Ps[8][16][88];   // per-wave P [q][t]

    const int tid  = threadIdx.x;
    const int wave = tid >> 6;
    const int lane = tid & 63;

    // XCD-aware remap over 512 blocks (all co-resident)
    const int n  = blockIdx.x + 8 * blockIdx.y;
    const int bh = (n & 7) + 8 * (n >> 6);
    const int qt = 7 - ((n >> 3) & 7);

    const int q0 = qt * 128;
    const size_t base_qk = (size_t)bh * S_DIM * M_DIM;
    const size_t base_v  = (size_t)bh * V_DIM * S_DIM;

    const int fr = lane & 15;        // q col (QK/PV); A-frag row index
    const int fg = lane >> 4;        // quad 0..3
    const int fk = fg * 8;           // frag k offset (bf16)

    // staging coords (512 threads)
    const int krow = tid >> 4, kcol = (tid & 15) * 8;   // K: 32 rows/pass, 2 passes
    const int vrow = tid >> 3, vcol = (tid & 7) * 8;    // V: 64 rows, 1 pass

    // ---- Q frags direct from global (one-shot; per-wave 16 distinct rows) ----
    short8 Bqr[4], Bqi[4];
    {
        const size_t qo = base_qk + (size_t)(q0 + wave * 16 + fr) * M_DIM + fk;
        #pragma unroll
        for (int ks = 0; ks < 4; ++ks) {
            Bqr[ks] = *(const short8*)&qr[qo + ks * 32];
            Bqi[ks] = *(const short8*)&qi[qo + ks * 32];
        }
    }

    f32x4 Ore[4], Oim[4];   // O^T[v = vt*16+fg*4+reg][q = fr]
    #pragma unroll
    for (int vt = 0; vt < 4; ++vt) {
        Ore[vt] = (f32x4){0.f, 0.f, 0.f, 0.f};
        Oim[vt] = (f32x4){0.f, 0.f, 0.f, 0.f};
    }
    float mrun = -INFINITY, lrun = 0.f;
    const int qglob = q0 + wave * 16 + fr;      // this lane's q
    const int qcap  = q0 + (wave >> 2) * 64;    // wave-uniform activity bound

    // ---- prefetch tile t0=0 into registers ----
    short8 pk[2][2], pv[2];
    #pragma unroll
    for (int pl = 0; pl < 2; ++pl) {
        const unsigned short* src = pl ? ki : kr;
        #pragma unroll
        for (int p = 0; p < 2; ++p)
            pk[pl][p] = *(const short8*)&src[base_qk + (size_t)(p * 32 + krow) * M_DIM + kcol];
    }
    #pragma unroll
    for (int pl = 0; pl < 2; ++pl) {
        const unsigned short* src = pl ? vit : vrt;
        pv[pl] = *(const short8*)&src[base_v + (size_t)vrow * S_DIM + vcol];
    }

    for (int t0 = 0; t0 <= q0 + 64; t0 += 64) {
        __syncthreads();   // prior tile's readers done
        // ---- commit prefetched K/V tile to LDS ----
        #pragma unroll
        for (int pl = 0; pl < 2; ++pl) {
            #pragma unroll
            for (int p = 0; p < 2; ++p)
                *(short8*)&Ks[pl][p * 32 + krow][kcol] = pk[pl][p];
            *(short8*)&Vs[pl][vrow][vcol] = pv[pl];
        }
        __syncthreads();

        // ---- issue next tile's global loads (consumed next iteration) ----
        if (t0 <= q0) {
            const int tn = t0 + 64;
            #pragma unroll
            for (int pl = 0; pl < 2; ++pl) {
                const unsigned short* src = pl ? ki : kr;
                #pragma unroll
                for (int p = 0; p < 2; ++p)
                    pk[pl][p] = *(const short8*)&src[base_qk + (size_t)(tn + p * 32 + krow) * M_DIM + kcol];
            }
            #pragma unroll
            for (int pl = 0; pl < 2; ++pl) {
                const unsigned short* src = pl ? vit : vrt;
                pv[pl] = *(const short8*)&src[base_v + (size_t)vrow * S_DIM + tn + vcol];
            }
        }

        // ---- wave-uniform skip of fully-masked final tile (waves 0-3) ----
        if (t0 > qcap) continue;

        // ---- S^T = K Q^T (complex): A = K frags, B = Q frags ----
        f32x4 Sre[4], Sim[4];   // t = tt*16 + fg*4 + reg, q = fr
        __builtin_amdgcn_s_setprio(1);
        #pragma unroll
        for (int tt = 0; tt < 4; ++tt) {
            Sre[tt] = (f32x4){0.f, 0.f, 0.f, 0.f};
            Sim[tt] = (f32x4){0.f, 0.f, 0.f, 0.f};
            const int trow = tt * 16 + fr;
            #pragma unroll
            for (int ks = 0; ks < 4; ++ks) {
                const short8 Akr = *(const short8*)&Ks[0][trow][ks * 32 + fk];
                const short8 Aki = *(const short8*)&Ks[1][trow][ks * 32 + fk];
                int4v t = *(int4v*)&Aki;
                t = t ^ (int)0x80008000;       // -Ki (transient)
                const short8 Akin = *(short8*)&t;
                Sre[tt] = __builtin_amdgcn_mfma_f32_16x16x32_bf16(Akr,  Bqr[ks], Sre[tt], 0, 0, 0);
                Sre[tt] = __builtin_amdgcn_mfma_f32_16x16x32_bf16(Akin, Bqi[ks], Sre[tt], 0, 0, 0);
                Sim[tt] = __builtin_amdgcn_mfma_f32_16x16x32_bf16(Akr,  Bqi[ks], Sim[tt], 0, 0, 0);
                Sim[tt] = __builtin_amdgcn_mfma_f32_16x16x32_bf16(Aki,  Bqr[ks], Sim[tt], 0, 0, 0);
            }
        }
        __builtin_amdgcn_s_setprio(0);

        // ---- amplitude + causal mask (amp overwrites Sre); in-lane + 2 quad shfls ----
        float rowmax = -INFINITY;
        #pragma unroll
        for (int tt = 0; tt < 4; ++tt) {
            #pragma unroll
            for (int r = 0; r < 4; ++r) {
                const int tg = t0 + tt * 16 + fg * 4 + r;
                const float re = Sre[tt][r], im = Sim[tt][r];
                const float a = sqrtf(re * re + im * im);   // scale pre-folded into q
                const float av = (tg > qglob) ? -INFINITY : a;
                Sre[tt][r] = av;
                rowmax = fmaxf(rowmax, av);
            }
        }
        rowmax = fmaxf(rowmax, __shfl_xor(rowmax, 16));
        rowmax = fmaxf(rowmax, __shfl_xor(rowmax, 32));

        // T13 defer-max: rescale only when the max grows materially
        if (!__all(rowmax - mrun <= 8.0f)) {
            const float nm = fmaxf(mrun, rowmax);
            const float alpha = __expf(mrun - nm);
            mrun = nm;
            lrun *= alpha;
            #pragma unroll
            for (int vt = 0; vt < 4; ++vt)
                #pragma unroll
                for (int r = 0; r < 4; ++r) { Ore[vt][r] *= alpha; Oim[vt][r] *= alpha; }
        }

        float psum = 0.f;
        #pragma unroll
        for (int tt = 0; tt < 4; ++tt) {
            const float p0 = __expf(Sre[tt][0] - mrun);
            const float p1 = __expf(Sre[tt][1] - mrun);
            const float p2 = __expf(Sre[tt][2] - mrun);
            const float p3 = __expf(Sre[tt][3] - mrun);
            psum += p0 + p1 + p2 + p3;
            ushort4 pw;
            pw.x = f2bf(p0); pw.y = f2bf(p1); pw.z = f2bf(p2); pw.w = f2bf(p3);
            *(ushort4*)&Ps[wave][fr][tt * 16 + fg * 4] = pw;
        }
        psum += __shfl_xor(psum, 16);
        psum += __shfl_xor(psum, 32);
        lrun += psum;

        // ---- O^T += V^T P^T : A = V^T frags (LDS), B = P frags (per-wave LDS) ----
        const short8 Bp0 = *(const short8*)&Ps[wave][fr][fk];
        const short8 Bp1 = *(const short8*)&Ps[wave][fr][32 + fk];
        __builtin_amdgcn_s_setprio(1);
        #pragma unroll
        for (int vt = 0; vt < 4; ++vt) {
            const int vr2 = vt * 16 + fr;
            const short8 Ar0 = *(const short8*)&Vs[0][vr2][fk];
            const short8 Ar1 = *(const short8*)&Vs[0][vr2][32 + fk];
            const short8 Ai0 = *(const short8*)&Vs[1][vr2][fk];
            const short8 Ai1 = *(const short8*)&Vs[1][vr2][32 + fk];
            Ore[vt] = __builtin_amdgcn_mfma_f32_16x16x32_bf16(Ar0, Bp0, Ore[vt], 0, 0, 0);
            Ore[vt] = __builtin_amdgcn_mfma_f32_16x16x32_bf16(Ar1, Bp1, Ore[vt], 0, 0, 0);
            Oim[vt] = __builtin_amdgcn_mfma_f32_16x16x32_bf16(Ai0, Bp0, Oim[vt], 0, 0, 0);
            Oim[vt] = __builtin_amdgcn_mfma_f32_16x16x32_bf16(Ai1, Bp1, Oim[vt], 0, 0, 0);
        }
        __builtin_amdgcn_s_setprio(0);
    }

    // ---- epilogue: lane owns q = qglob; v = vt*16 + fg*4 + reg ----
    const int b = bh >> 4, h = bh & 15;
    const float inv = 1.0f / lrun;
    const size_t base = ((size_t)(qglob * B_DIM + b)) * E_DIM + h * V_DIM;
    #pragma unroll
    for (int vt = 0; vt < 4; ++vt) {
        ushort4 pr, pi;
        pr.x = f2bf(Ore[vt][0] * inv); pr.y = f2bf(Ore[vt][1] * inv);
        pr.z = f2bf(Ore[vt][2] * inv); pr.w = f2bf(Ore[vt][3] * inv);
        pi.x = f2bf(Oim[vt][0] * inv); pi.y = f2bf(Oim[vt][1] * inv);
        pi.z = f2bf(Oim[vt][2] * inv); pi.w = f2bf(Oim[vt][3] * inv);
        *(ushort4*)&updre[base + vt * 16 + fg * 4] = pr;
        *(ushort4*)&updim[base + vt * 16 + fg * 4] = pi;
    }
}

extern "C" void kernel_launch(void* const* d_in, const int* in_sizes, int n_in,
                              void* d_out, int out_size, void* d_ws, size_t ws_size,
                              hipStream_t stream) {
    const float* xre  = (const float*)d_in[0];
    const float* xim  = (const float*)d_in[1];
    const float* wqre = (const float*)d_in[2];
    const float* wqim = (const float*)d_in[3];
    const float* wkre = (const float*)d_in[4];
    const float* wkim = (const float*)d_in[5];
    const float* wvre = (const float*)d_in[6];
    const float* wvim = (const float*)d_in[7];
    const float* wore = (const float*)d_in[8];
    const float* woim = (const float*)d_in[9];
    float* out = (float*)d_out;

    // workspace layout (~160 MB)
    char* p = (char*)d_ws;
    const size_t QK = (size_t)B_DIM * H_DIM * S_DIM * M_DIM;   // 8.39M
    const size_t VS = (size_t)B_DIM * H_DIM * S_DIM * V_DIM;   // 4.19M
    const size_t SBE = (size_t)S_DIM * B_DIM * E_DIM;          // 4.19M
    unsigned short* qrw = (unsigned short*)p;  p += QK * 2;
    unsigned short* qiw = (unsigned short*)p;  p += QK * 2;
    unsigned short* krw = (unsigned short*)p;  p += QK * 2;
    unsigned short* kiw = (unsigned short*)p;  p += QK * 2;
    unsigned short* vrw = (unsigned short*)p;  p += VS * 2;
    unsigned short* viw = (unsigned short*)p;  p += VS * 2;
    unsigned short* vrt = (unsigned short*)p;  p += VS * 2;
    unsigned short* vit = (unsigned short*)p;  p += VS * 2;
    unsigned short* updre = (unsigned short*)p; p += SBE * 2;
    unsigned short* updim = (unsigned short*)p; p += SBE * 2;
    unsigned short* xbre  = (unsigned short*)p; p += SBE * 2;
    unsigned short* xbim  = (unsigned short*)p; p += SBE * 2;
    unsigned short* wbre  = (unsigned short*)p; p += (size_t)5120 * E_DIM * 2;
    unsigned short* wbim  = (unsigned short*)p; p += (size_t)5120 * E_DIM * 2;
    unsigned short* wtre  = (unsigned short*)p; p += (size_t)E_DIM * E_DIM * 2;
    unsigned short* wtim  = (unsigned short*)p; p += (size_t)E_DIM * E_DIM * 2;

    // bf16 conversion (single fused launch) + wo transpose
    convert_all<<<9216, 256, 0, stream>>>(xre, xim, wqre, wqim, wkre, wkim, wvre, wvim,
                                          xbre, xbim, wbre, wbim);
    transpose_wo<<<dim3(32, 32), 256, 0, stream>>>(wore, woim, wtre, wtim);

    // QKV projection (bf16 MFMA 16x16x32, 64x64 wave tile, T3-min dbuf)
    cgemm<0><<<dim3(32, 40), 256, 0, stream>>>(xbre, xbim, wbre, wbim,
                                               qrw, qiw, krw, kiw, vrw, viw,
                                               nullptr, nullptr, nullptr);
    // V -> V^T planes
    vtrans<<<dim3(16, 64), 256, 0, stream>>>(vrw, viw, vrt, vit);
    // MFMA flash attention (QBLK=128, 8 waves, staged LDS, XCD remap)
    attn_mfma<<<dim3(8, 64), 512, 0, stream>>>(qrw, qiw, krw, kiw, vrt, vit, updre, updim);
    // output projection + residual (BM=64 tile -> 512 blocks, 3 blocks/CU)
    cgemm<1><<<dim3(64, 8), 256, 0, stream>>>(updre, updim, wtre, wtim,
                                              nullptr, nullptr, nullptr, nullptr, nullptr, nullptr,
                                              xre, xim, out);
}

// Round 9
// 456.155 us; speedup vs baseline: 1.0625x; 1.0625x over previous
//
#include <hip/hip_runtime.h>
#include <math.h>

#define S_DIM 1024
#define B_DIM 4
#define E_DIM 1024
#define H_DIM 16
#define M_DIM 128
#define V_DIM 64

typedef __attribute__((ext_vector_type(8))) short short8;
typedef __attribute__((ext_vector_type(4))) float f32x4;
typedef __attribute__((ext_vector_type(4))) int int4v;

__device__ __forceinline__ unsigned short f2bf(float f) {
    union { float f; unsigned u; } v; v.f = f;
    unsigned r = v.u + 0x7FFFu + ((v.u >> 16) & 1u);   // round-to-nearest-even
    return (unsigned short)(r >> 16);
}

__device__ __forceinline__ void async16(const unsigned short* g, unsigned short* l) {
    __builtin_amdgcn_global_load_lds(
        (const __attribute__((address_space(1))) void*)g,
        (__attribute__((address_space(3))) void*)l,
        16, 0, 0);
}

// ---------------- convert: fp32 (re,im) -> bf16, all 4 tensors in one launch ----------------
// segments (in float4 units): x 1048576 | wq 524288 | wk 524288 | wv 262144
__global__ __launch_bounds__(256) void convert_all(
    const float* __restrict__ xre,  const float* __restrict__ xim,
    const float* __restrict__ wqre, const float* __restrict__ wqim,
    const float* __restrict__ wkre, const float* __restrict__ wkim,
    const float* __restrict__ wvre, const float* __restrict__ wvim,
    unsigned short* __restrict__ xbre, unsigned short* __restrict__ xbim,
    unsigned short* __restrict__ wbre, unsigned short* __restrict__ wbim)
{
    const int i = blockIdx.x * 256 + threadIdx.x;
    const float *re, *im;
    unsigned short *dr, *di;
    int j;
    if (i < 1048576)      { re = xre;  im = xim;  dr = xbre;               di = xbim;               j = i; }
    else if (i < 1572864) { re = wqre; im = wqim; dr = wbre;               di = wbim;               j = i - 1048576; }
    else if (i < 2097152) { re = wkre; im = wkim; dr = wbre + 2048 * 1024; di = wbim + 2048 * 1024; j = i - 1572864; }
    else                  { re = wvre; im = wvim; dr = wbre + 4096 * 1024; di = wbim + 4096 * 1024; j = i - 2097152; }
    float4 r = ((const float4*)re)[j];
    float4 m = ((const float4*)im)[j];
    ushort4 ro, mo;
    ro.x = f2bf(r.x); ro.y = f2bf(r.y); ro.z = f2bf(r.z); ro.w = f2bf(r.w);
    mo.x = f2bf(m.x); mo.y = f2bf(m.y); mo.z = f2bf(m.z); mo.w = f2bf(m.w);
    ((ushort4*)dr)[j] = ro;
    ((ushort4*)di)[j] = mo;
}

// wo (e,f) -> woT (f,e) bf16
__global__ __launch_bounds__(256) void transpose_wo(
    const float* __restrict__ wore, const float* __restrict__ woim,
    unsigned short* __restrict__ wtre, unsigned short* __restrict__ wtim)
{
    __shared__ float tr[32][33], ti[32][33];
    const int bx = blockIdx.x * 32;   // e range
    const int by = blockIdx.y * 32;   // f range
    const int tx = threadIdx.x & 31, ty = threadIdx.x >> 5;
    for (int i = ty; i < 32; i += 8) {
        tr[i][tx] = wore[(bx + i) * E_DIM + by + tx];
        ti[i][tx] = woim[(bx + i) * E_DIM + by + tx];
    }
    __syncthreads();
    for (int i = ty; i < 32; i += 8) {
        wtre[(by + i) * E_DIM + bx + tx] = f2bf(tr[tx][i]);
        wtim[(by + i) * E_DIM + bx + tx] = f2bf(ti[tx][i]);
    }
}

// v planes [bh][t][64] -> v^T planes [bh][v][1024]
__global__ __launch_bounds__(256) void vtrans(
    const unsigned short* __restrict__ vrp, const unsigned short* __restrict__ vip,
    unsigned short* __restrict__ vrt, unsigned short* __restrict__ vit)
{
    __shared__ unsigned short tl[2][64][66];
    const int tid = threadIdx.x;
    const int t0 = blockIdx.x * 64;
    const int bh = blockIdx.y;
    #pragma unroll
    for (int pl = 0; pl < 2; ++pl) {
        const unsigned short* src = pl ? vip : vrp;
        #pragma unroll
        for (int p = 0; p < 2; ++p) {
            const int row = p * 32 + (tid >> 3);
            const int col = (tid & 7) * 8;
            short8 d = *(const short8*)&src[((size_t)bh * S_DIM + t0 + row) * V_DIM + col];
            #pragma unroll
            for (int j = 0; j < 8; ++j) tl[pl][row][col + j] = (unsigned short)d[j];
        }
    }
    __syncthreads();
    #pragma unroll
    for (int pl = 0; pl < 2; ++pl) {
        unsigned short* dst = pl ? vit : vrt;
        #pragma unroll
        for (int p = 0; p < 2; ++p) {
            const int v = p * 32 + (tid >> 3);
            const int tc = (tid & 7) * 8;
            short8 d;
            #pragma unroll
            for (int j = 0; j < 8; ++j) d[j] = (short)tl[pl][tc + j][v];
            *(short8*)&dst[((size_t)bh * V_DIM + v) * S_DIM + t0 + tc] = d;
        }
    }
}

// ---------------- complex bf16 MFMA GEMM: C = A * B^T ----------------
// MODE 0 (frozen since round 5: 154 us, MfmaUtil 52%, 0 bank conflicts):
// block 128x128, 4 waves (2x2), wave tile 64x64, 16x16x32 frags, BK=32,
// T3-min double-buffer, chunk-XOR swizzle. qscale folded into q epilogue.
// MODE 1 (kept from round 8, correctness-verified): BM=64 tile (wave tile
// 32x64, 48 KB LDS, 3 blocks/CU) -> 512 blocks -> cross-block overlap of the
// vmcnt(0) drain (the 128-tile gave 256 blocks = 1/CU = no overlap partner).
template<int MODE>
__global__ __launch_bounds__(256, MODE ? 3 : 2) void cgemm(
    const unsigned short* __restrict__ Are, const unsigned short* __restrict__ Aim,
    const unsigned short* __restrict__ Bre, const unsigned short* __restrict__ Bim,
    unsigned short* __restrict__ qrp, unsigned short* __restrict__ qip,
    unsigned short* __restrict__ krp, unsigned short* __restrict__ kip,
    unsigned short* __restrict__ vrp, unsigned short* __restrict__ vip,
    const float* __restrict__ xre, const float* __restrict__ xim,
    float* __restrict__ out)
{
    constexpr int BM  = MODE ? 64 : 128;       // block M rows
    constexpr int IM  = MODE ? 2 : 4;          // wave m-frag count
    constexpr int ASZ = BM * 32;               // A plane elems per slice buffer
    constexpr int BUF = 2 * ASZ + 8192;        // elems per slice buffer (A*2 + B*2)
    __shared__ __align__(16) unsigned short lds[2 * BUF];
    const int tid  = threadIdx.x;
    const int wave = tid >> 6;
    const int lane = tid & 63;
    const int r0 = blockIdx.x * BM;
    const int j0 = blockIdx.y * 128;
    const int wm = (wave >> 1) * (MODE ? 32 : 64);   // m part
    const int wn = (wave & 1) * 64;                  // n half

    f32x4 accre[IM][4], accim[IM][4];
    #pragma unroll
    for (int i = 0; i < IM; ++i)
        #pragma unroll
        for (int j = 0; j < 4; ++j) {
            accre[i][j] = (f32x4){0.f, 0.f, 0.f, 0.f};
            accim[i][j] = (f32x4){0.f, 0.f, 0.f, 0.f};
        }

    const int sr   = tid >> 2;
    const int sc   = (tid & 3) * 8;                          // physical chunk (shorts)
    const int scol = ((tid & 3) ^ ((tid >> 3) & 3)) * 8;     // pre-swizzled source col

    const int fr = lane & 15;                                // frag m/n index
    const int xc = ((lane >> 4) ^ ((lane >> 1) & 3)) * 8;    // swizzled k-chunk on read

    #define STAGE(sl, bb) { \
        const int kg = (sl) * 32; \
        unsigned short* b_ = &lds[(bb) * BUF]; \
        const size_t ga0 = (size_t)(r0 + sr) * E_DIM + kg + scol; \
        const size_t gb0 = (size_t)(j0 + sr) * E_DIM + kg + scol; \
        const size_t gb1 = (size_t)(j0 + 64 + sr) * E_DIM + kg + scol; \
        async16(Are + ga0, b_ + sr * 32 + sc); \
        async16(Aim + ga0, b_ + ASZ + sr * 32 + sc); \
        if (MODE == 0) { \
            const size_t ga1 = (size_t)(r0 + 64 + sr) * E_DIM + kg + scol; \
            async16(Are + ga1, b_ + (64 + sr) * 32 + sc); \
            async16(Aim + ga1, b_ + ASZ + (64 + sr) * 32 + sc); \
        } \
        async16(Bre + gb0, b_ + 2 * ASZ + sr * 32 + sc); \
        async16(Bre + gb1, b_ + 2 * ASZ + (64 + sr) * 32 + sc); \
        async16(Bim + gb0, b_ + 2 * ASZ + 4096 + sr * 32 + sc); \
        async16(Bim + gb1, b_ + 2 * ASZ + 4096 + (64 + sr) * 32 + sc); }

    STAGE(0, 0)
    asm volatile("s_waitcnt vmcnt(0)" ::: "memory");
    __builtin_amdgcn_s_barrier();

    #pragma unroll 1
    for (int s = 0; s < 32; ++s) {
        if (s < 31) STAGE(s + 1, (s + 1) & 1)

        const unsigned short* buf = &lds[(s & 1) * BUF];
        short8 ar[IM], ai[IM];
        #pragma unroll
        for (int im = 0; im < IM; ++im) {
            const int ro = (wm + im * 16 + fr) * 32 + xc;
            ar[im] = *(const short8*)&buf[ro];
            ai[im] = *(const short8*)&buf[ASZ + ro];
        }
        #pragma unroll
        for (int jn = 0; jn < 4; ++jn) {
            const int ro = (wn + jn * 16 + fr) * 32 + xc;
            const short8 br = *(const short8*)&buf[2 * ASZ + ro];
            const short8 bi = *(const short8*)&buf[2 * ASZ + 4096 + ro];
            int4v t = *(int4v*)&bi;
            t = t ^ (int)0x80008000;       // bin = -bi (transient)
            const short8 bin = *(short8*)&t;
            #pragma unroll
            for (int im = 0; im < IM; ++im) {
                accre[im][jn] = __builtin_amdgcn_mfma_f32_16x16x32_bf16(ar[im], br,  accre[im][jn], 0, 0, 0);
                accre[im][jn] = __builtin_amdgcn_mfma_f32_16x16x32_bf16(ai[im], bin, accre[im][jn], 0, 0, 0);
                accim[im][jn] = __builtin_amdgcn_mfma_f32_16x16x32_bf16(ar[im], bi,  accim[im][jn], 0, 0, 0);
                accim[im][jn] = __builtin_amdgcn_mfma_f32_16x16x32_bf16(ai[im], br,  accim[im][jn], 0, 0, 0);
            }
        }

        if (s < 31) {
            asm volatile("s_waitcnt vmcnt(0)" ::: "memory");
            __builtin_amdgcn_s_barrier();
        }
    }
    #undef STAGE

    // epilogue: D row = (lane>>4)*4+reg, col = lane&15  [measured m89/m91]
    const float qscale = 0.088388347648318447f;  // 1/sqrt(128), folded into q planes
    #pragma unroll
    for (int im = 0; im < IM; ++im) {
        #pragma unroll
        for (int reg = 0; reg < 4; ++reg) {
            const int r = r0 + wm + im * 16 + (lane >> 4) * 4 + reg;
            #pragma unroll
            for (int jn = 0; jn < 4; ++jn) {
                const int j = j0 + wn + jn * 16 + fr;
                const float vr = accre[im][jn][reg];
                const float vi = accim[im][jn][reg];
                if (MODE == 0) {
                    const int s = r >> 2, b = r & 3;   // r = s*B + b
                    if (j < 2048) {
                        const int h = j >> 7, m = j & 127;
                        const size_t off = ((size_t)(b * H_DIM + h) * S_DIM + s) * M_DIM + m;
                        qrp[off] = f2bf(vr * qscale); qip[off] = f2bf(vi * qscale);
                    } else if (j < 4096) {
                        const int jl = j - 2048, h = jl >> 7, m = jl & 127;
                        const size_t off = ((size_t)(b * H_DIM + h) * S_DIM + s) * M_DIM + m;
                        krp[off] = f2bf(vr); kip[off] = f2bf(vi);
                    } else {
                        const int jl = j - 4096, h = jl >> 6, vv = jl & 63;
                        const size_t off = ((size_t)(b * H_DIM + h) * S_DIM + s) * V_DIM + vv;
                        vrp[off] = f2bf(vr); vip[off] = f2bf(vi);
                    }
                } else {
                    const int idx = r * E_DIM + j;
                    out[idx] = vr + xre[idx];
                    out[S_DIM * B_DIM * E_DIM + idx] = vi + xim[idx];
                }
            }
        }
    }
}

// ---------------- K2: MFMA flash attention, S^T orientation ----------------
// Round-9: exact revert to the round-7 attention (measured inside the 449.9us
// best total). Round-8's 512-thread QBLK=128 variant spilled: launch_bounds
// (512,4) capped VGPR at 128 < ~150 needed -> VGPR_Count 64 + 222 MB scratch
// writes + MfmaUtil 10.6%. This 256-thread structure fits in 2 blocks/CU
// without spill. Staged LDS K/V (1x per-block traffic), XCD-aware bh remap,
// folded qscale, T13 defer-max, packed ushort4 Ps (pitch 88), setprio.
__global__ __launch_bounds__(256, 2) void attn_mfma(
    const unsigned short* __restrict__ qr, const unsigned short* __restrict__ qi,
    const unsigned short* __restrict__ kr, const unsigned short* __restrict__ ki,
    const unsigned short* __restrict__ vrt, const unsigned short* __restrict__ vit,
    unsigned short* __restrict__ updre, unsigned short* __restrict__ updim)
{
    __shared__ __align__(16) unsigned short Ks[2][64][136];  // K tile [plane][t][m] (Q staged here first)
    __shared__ __align__(16) unsigned short Vs[2][64][72];   // V^T tile [plane][v][t]
    __shared__ __align__(16) unsigned short Ps[4][16][88];   // per-wave P [q][t], pitch 88

    const int tid  = threadIdx.x;
    const int wave = tid >> 6;
    const int lane = tid & 63;

    // XCD-aware remap: n%8 ~ XCD; each XCD gets bh = {xcd, xcd+8, ..., xcd+56},
    // 16 consecutive blocks per bh (long qt dispatched first within each bh).
    const int n  = blockIdx.x + 16 * blockIdx.y;
    const int m_ = n >> 3;
    const int bh = (n & 7) + 8 * (m_ >> 4);
    const int qt = 15 - (m_ & 15);

    const int q0 = qt * 64;
    const size_t base_qk = (size_t)bh * S_DIM * M_DIM;
    const size_t base_v  = (size_t)bh * V_DIM * S_DIM;

    const int fr = lane & 15;        // q col (QK/PV); A-frag row index
    const int fg = lane >> 4;        // quad 0..3
    const int fk = fg * 8;           // frag k offset (bf16)

    // staging coords
    const int krow = tid >> 4, kcol = (tid & 15) * 8;   // K: 16 rows/pass
    const int vrow = tid >> 3, vcol = (tid & 7) * 8;    // V: 32 rows/pass

    // ---- stage Q tile into Ks, extract per-wave B-frags (Q[q=fr][m]) ----
    #pragma unroll
    for (int pl = 0; pl < 2; ++pl) {
        const unsigned short* src = pl ? qi : qr;
        #pragma unroll
        for (int p = 0; p < 4; ++p)
            *(short8*)&Ks[pl][p * 16 + krow][kcol] =
                *(const short8*)&src[base_qk + (size_t)(q0 + p * 16 + krow) * M_DIM + kcol];
    }
    __syncthreads();
    short8 Bqr[4], Bqi[4];
    {
        const int qrow = wave * 16 + fr;
        #pragma unroll
        for (int ks = 0; ks < 4; ++ks) {
            Bqr[ks] = *(const short8*)&Ks[0][qrow][ks * 32 + fk];
            Bqi[ks] = *(const short8*)&Ks[1][qrow][ks * 32 + fk];
        }
    }

    f32x4 Ore[4], Oim[4];   // O^T[v = vt*16+fg*4+reg][q = fr]
    #pragma unroll
    for (int vt = 0; vt < 4; ++vt) {
        Ore[vt] = (f32x4){0.f, 0.f, 0.f, 0.f};
        Oim[vt] = (f32x4){0.f, 0.f, 0.f, 0.f};
    }
    float mrun = -INFINITY, lrun = 0.f;
    const int qglob = q0 + wave * 16 + fr;      // this lane's q

    // ---- prefetch tile t0=0 into registers ----
    short8 pk[2][4], pv[2][2];
    #pragma unroll
    for (int pl = 0; pl < 2; ++pl) {
        const unsigned short* src = pl ? ki : kr;
        #pragma unroll
        for (int p = 0; p < 4; ++p)
            pk[pl][p] = *(const short8*)&src[base_qk + (size_t)(p * 16 + krow) * M_DIM + kcol];
    }
    #pragma unroll
    for (int pl = 0; pl < 2; ++pl) {
        const unsigned short* src = pl ? vit : vrt;
        #pragma unroll
        for (int p = 0; p < 2; ++p)
            pv[pl][p] = *(const short8*)&src[base_v + (size_t)(p * 32 + vrow) * S_DIM + vcol];
    }

    for (int t0 = 0; t0 <= q0; t0 += 64) {
        __syncthreads();   // prior readers of Ks/Vs done (iter0: Q frags extracted)
        // ---- commit prefetched K/V tile to LDS ----
        #pragma unroll
        for (int pl = 0; pl < 2; ++pl) {
            #pragma unroll
            for (int p = 0; p < 4; ++p)
                *(short8*)&Ks[pl][p * 16 + krow][kcol] = pk[pl][p];
            #pragma unroll
            for (int p = 0; p < 2; ++p)
                *(short8*)&Vs[pl][p * 32 + vrow][vcol] = pv[pl][p];
        }
        __syncthreads();

        // ---- issue next tile's global loads (consumed next iteration) ----
        if (t0 + 64 <= q0) {
            const int tn = t0 + 64;
            #pragma unroll
            for (int pl = 0; pl < 2; ++pl) {
                const unsigned short* src = pl ? ki : kr;
                #pragma unroll
                for (int p = 0; p < 4; ++p)
                    pk[pl][p] = *(const short8*)&src[base_qk + (size_t)(tn + p * 16 + krow) * M_DIM + kcol];
            }
            #pragma unroll
            for (int pl = 0; pl < 2; ++pl) {
                const unsigned short* src = pl ? vit : vrt;
                #pragma unroll
                for (int p = 0; p < 2; ++p)
                    pv[pl][p] = *(const short8*)&src[base_v + (size_t)(p * 32 + vrow) * S_DIM + tn + vcol];
            }
        }

        // ---- S^T = K Q^T (complex): A = K frags, B = Q frags ----
        f32x4 Sre[4], Sim[4];   // t = tt*16 + fg*4 + reg, q = fr
        __builtin_amdgcn_s_setprio(1);
        #pragma unroll
        for (int tt = 0; tt < 4; ++tt) {
            Sre[tt] = (f32x4){0.f, 0.f, 0.f, 0.f};
            Sim[tt] = (f32x4){0.f, 0.f, 0.f, 0.f};
            const int trow = tt * 16 + fr;
            #pragma unroll
            for (int ks = 0; ks < 4; ++ks) {
                const short8 Akr = *(const short8*)&Ks[0][trow][ks * 32 + fk];
                const short8 Aki = *(const short8*)&Ks[1][trow][ks * 32 + fk];
                int4v t = *(int4v*)&Aki;
                t = t ^ (int)0x80008000;       // -Ki (transient)
                const short8 Akin = *(short8*)&t;
                Sre[tt] = __builtin_amdgcn_mfma_f32_16x16x32_bf16(Akr,  Bqr[ks], Sre[tt], 0, 0, 0);
                Sre[tt] = __builtin_amdgcn_mfma_f32_16x16x32_bf16(Akin, Bqi[ks], Sre[tt], 0, 0, 0);
                Sim[tt] = __builtin_amdgcn_mfma_f32_16x16x32_bf16(Akr,  Bqi[ks], Sim[tt], 0, 0, 0);
                Sim[tt] = __builtin_amdgcn_mfma_f32_16x16x32_bf16(Aki,  Bqr[ks], Sim[tt], 0, 0, 0);
            }
        }
        __builtin_amdgcn_s_setprio(0);

        // ---- amplitude + causal mask (amp overwrites Sre); in-lane + 2 quad shfls ----
        float rowmax = -INFINITY;
        #pragma unroll
        for (int tt = 0; tt < 4; ++tt) {
            #pragma unroll
            for (int r = 0; r < 4; ++r) {
                const int tg = t0 + tt * 16 + fg * 4 + r;
                const float re = Sre[tt][r], im = Sim[tt][r];
                const float a = sqrtf(re * re + im * im);   // scale pre-folded into q
                const float av = (tg > qglob) ? -INFINITY : a;
                Sre[tt][r] = av;
                rowmax = fmaxf(rowmax, av);
            }
        }
        rowmax = fmaxf(rowmax, __shfl_xor(rowmax, 16));
        rowmax = fmaxf(rowmax, __shfl_xor(rowmax, 32));

        // T13 defer-max: rescale only when the max grows materially
        if (!__all(rowmax - mrun <= 8.0f)) {
            const float nm = fmaxf(mrun, rowmax);
            const float alpha = __expf(mrun - nm);
            mrun = nm;
            lrun *= alpha;
            #pragma unroll
            for (int vt = 0; vt < 4; ++vt)
                #pragma unroll
                for (int r = 0; r < 4; ++r) { Ore[vt][r] *= alpha; Oim[vt][r] *= alpha; }
        }

        float psum = 0.f;
        #pragma unroll
        for (int tt = 0; tt < 4; ++tt) {
            const float p0 = __expf(Sre[tt][0] - mrun);
            const float p1 = __expf(Sre[tt][1] - mrun);
            const float p2 = __expf(Sre[tt][2] - mrun);
            const float p3 = __expf(Sre[tt][3] - mrun);
            psum += p0 + p1 + p2 + p3;
            ushort4 pw;
            pw.x = f2bf(p0); pw.y = f2bf(p1); pw.z = f2bf(p2); pw.w = f2bf(p3);
            *(ushort4*)&Ps[wave][fr][tt * 16 + fg * 4] = pw;
        }
        psum += __shfl_xor(psum, 16);
        psum += __shfl_xor(psum, 32);
        lrun += psum;

        // ---- O^T += V^T P^T : A = V^T frags (LDS), B = P frags (per-wave LDS) ----
        const short8 Bp0 = *(const short8*)&Ps[wave][fr][fk];
        const short8 Bp1 = *(const short8*)&Ps[wave][fr][32 + fk];
        __builtin_amdgcn_s_setprio(1);
        #pragma unroll
        for (int vt = 0; vt < 4; ++vt) {
            const int vr2 = vt * 16 + fr;
            const short8 Ar0 = *(const short8*)&Vs[0][vr2][fk];
            const short8 Ar1 = *(const short8*)&Vs[0][vr2][32 + fk];
            const short8 Ai0 = *(const short8*)&Vs[1][vr2][fk];
            const short8 Ai1 = *(const short8*)&Vs[1][vr2][32 + fk];
            Ore[vt] = __builtin_amdgcn_mfma_f32_16x16x32_bf16(Ar0, Bp0, Ore[vt], 0, 0, 0);
            Ore[vt] = __builtin_amdgcn_mfma_f32_16x16x32_bf16(Ar1, Bp1, Ore[vt], 0, 0, 0);
            Oim[vt] = __builtin_amdgcn_mfma_f32_16x16x32_bf16(Ai0, Bp0, Oim[vt], 0, 0, 0);
            Oim[vt] = __builtin_amdgcn_mfma_f32_16x16x32_bf16(Ai1, Bp1, Oim[vt], 0, 0, 0);
        }
        __builtin_amdgcn_s_setprio(0);
    }

    // ---- epilogue: lane owns q = qglob; v = vt*16 + fg*4 + reg ----
    const int b = bh >> 4, h = bh & 15;
    const float inv = 1.0f / lrun;
    const size_t base = ((size_t)(qglob * B_DIM + b)) * E_DIM + h * V_DIM;
    #pragma unroll
    for (int vt = 0; vt < 4; ++vt) {
        ushort4 pr, pi;
        pr.x = f2bf(Ore[vt][0] * inv); pr.y = f2bf(Ore[vt][1] * inv);
        pr.z = f2bf(Ore[vt][2] * inv); pr.w = f2bf(Ore[vt][3] * inv);
        pi.x = f2bf(Oim[vt][0] * inv); pi.y = f2bf(Oim[vt][1] * inv);
        pi.z = f2bf(Oim[vt][2] * inv); pi.w = f2bf(Oim[vt][3] * inv);
        *(ushort4*)&updre[base + vt * 16 + fg * 4] = pr;
        *(ushort4*)&updim[base + vt * 16 + fg * 4] = pi;
    }
}

extern "C" void kernel_launch(void* const* d_in, const int* in_sizes, int n_in,
                              void* d_out, int out_size, void* d_ws, size_t ws_size,
                              hipStream_t stream) {
    const float* xre  = (const float*)d_in[0];
    const float* xim  = (const float*)d_in[1];
    const float* wqre = (const float*)d_in[2];
    const float* wqim = (const float*)d_in[3];
    const float* wkre = (const float*)d_in[4];
    const float* wkim = (const float*)d_in[5];
    const float* wvre = (const float*)d_in[6];
    const float* wvim = (const float*)d_in[7];
    const float* wore = (const float*)d_in[8];
    const float* woim = (const float*)d_in[9];
    float* out = (float*)d_out;

    // workspace layout (~160 MB)
    char* p = (char*)d_ws;
    const size_t QK = (size_t)B_DIM * H_DIM * S_DIM * M_DIM;   // 8.39M
    const size_t VS = (size_t)B_DIM * H_DIM * S_DIM * V_DIM;   // 4.19M
    const size_t SBE = (size_t)S_DIM * B_DIM * E_DIM;          // 4.19M
    unsigned short* qrw = (unsigned short*)p;  p += QK * 2;
    unsigned short* qiw = (unsigned short*)p;  p += QK * 2;
    unsigned short* krw = (unsigned short*)p;  p += QK * 2;
    unsigned short* kiw = (unsigned short*)p;  p += QK * 2;
    unsigned short* vrw = (unsigned short*)p;  p += VS * 2;
    unsigned short* viw = (unsigned short*)p;  p += VS * 2;
    unsigned short* vrt = (unsigned short*)p;  p += VS * 2;
    unsigned short* vit = (unsigned short*)p;  p += VS * 2;
    unsigned short* updre = (unsigned short*)p; p += SBE * 2;
    unsigned short* updim = (unsigned short*)p; p += SBE * 2;
    unsigned short* xbre  = (unsigned short*)p; p += SBE * 2;
    unsigned short* xbim  = (unsigned short*)p; p += SBE * 2;
    unsigned short* wbre  = (unsigned short*)p; p += (size_t)5120 * E_DIM * 2;
    unsigned short* wbim  = (unsigned short*)p; p += (size_t)5120 * E_DIM * 2;
    unsigned short* wtre  = (unsigned short*)p; p += (size_t)E_DIM * E_DIM * 2;
    unsigned short* wtim  = (unsigned short*)p; p += (size_t)E_DIM * E_DIM * 2;

    // bf16 conversion (single fused launch) + wo transpose
    convert_all<<<9216, 256, 0, stream>>>(xre, xim, wqre, wqim, wkre, wkim, wvre, wvim,
                                          xbre, xbim, wbre, wbim);
    transpose_wo<<<dim3(32, 32), 256, 0, stream>>>(wore, woim, wtre, wtim);

    // QKV projection (bf16 MFMA 16x16x32, 64x64 wave tile, T3-min dbuf)
    cgemm<0><<<dim3(32, 40), 256, 0, stream>>>(xbre, xbim, wbre, wbim,
                                               qrw, qiw, krw, kiw, vrw, viw,
                                               nullptr, nullptr, nullptr);
    // V -> V^T planes
    vtrans<<<dim3(16, 64), 256, 0, stream>>>(vrw, viw, vrt, vit);
    // MFMA flash attention (round-7 structure: staged LDS + XCD-aware bh clustering)
    attn_mfma<<<dim3(16, 64), 256, 0, stream>>>(qrw, qiw, krw, kiw, vrt, vit, updre, updim);
    // output projection + residual (BM=64 tile -> 512 blocks, 3 blocks/CU)
    cgemm<1><<<dim3(64, 8), 256, 0, stream>>>(updre, updim, wtre, wtim,
                                              nullptr, nullptr, nullptr, nullptr, nullptr, nullptr,
                                              xre, xim, out);
}

// Round 10
// 423.009 us; speedup vs baseline: 1.1458x; 1.0784x over previous
//
#include <hip/hip_runtime.h>
#include <math.h>

#define S_DIM 1024
#define B_DIM 4
#define E_DIM 1024
#define H_DIM 16
#define M_DIM 128
#define V_DIM 64

typedef __attribute__((ext_vector_type(8))) short short8;
typedef __attribute__((ext_vector_type(4))) float f32x4;
typedef __attribute__((ext_vector_type(4))) int int4v;

__device__ __forceinline__ unsigned short f2bf(float f) {
    union { float f; unsigned u; } v; v.f = f;
    unsigned r = v.u + 0x7FFFu + ((v.u >> 16) & 1u);   // round-to-nearest-even
    return (unsigned short)(r >> 16);
}

__device__ __forceinline__ void async16(const unsigned short* g, unsigned short* l) {
    __builtin_amdgcn_global_load_lds(
        (const __attribute__((address_space(1))) void*)g,
        (__attribute__((address_space(3))) void*)l,
        16, 0, 0);
}

// ---------------- convert: fp32 (re,im) -> bf16, all 4 tensors in one launch ----------------
// segments (in float4 units): x 1048576 | wq 524288 | wk 524288 | wv 262144
__global__ __launch_bounds__(256) void convert_all(
    const float* __restrict__ xre,  const float* __restrict__ xim,
    const float* __restrict__ wqre, const float* __restrict__ wqim,
    const float* __restrict__ wkre, const float* __restrict__ wkim,
    const float* __restrict__ wvre, const float* __restrict__ wvim,
    unsigned short* __restrict__ xbre, unsigned short* __restrict__ xbim,
    unsigned short* __restrict__ wbre, unsigned short* __restrict__ wbim)
{
    const int i = blockIdx.x * 256 + threadIdx.x;
    const float *re, *im;
    unsigned short *dr, *di;
    int j;
    if (i < 1048576)      { re = xre;  im = xim;  dr = xbre;               di = xbim;               j = i; }
    else if (i < 1572864) { re = wqre; im = wqim; dr = wbre;               di = wbim;               j = i - 1048576; }
    else if (i < 2097152) { re = wkre; im = wkim; dr = wbre + 2048 * 1024; di = wbim + 2048 * 1024; j = i - 1572864; }
    else                  { re = wvre; im = wvim; dr = wbre + 4096 * 1024; di = wbim + 4096 * 1024; j = i - 2097152; }
    float4 r = ((const float4*)re)[j];
    float4 m = ((const float4*)im)[j];
    ushort4 ro, mo;
    ro.x = f2bf(r.x); ro.y = f2bf(r.y); ro.z = f2bf(r.z); ro.w = f2bf(r.w);
    mo.x = f2bf(m.x); mo.y = f2bf(m.y); mo.z = f2bf(m.z); mo.w = f2bf(m.w);
    ((ushort4*)dr)[j] = ro;
    ((ushort4*)di)[j] = mo;
}

// wo (e,f) -> woT (f,e) bf16
__global__ __launch_bounds__(256) void transpose_wo(
    const float* __restrict__ wore, const float* __restrict__ woim,
    unsigned short* __restrict__ wtre, unsigned short* __restrict__ wtim)
{
    __shared__ float tr[32][33], ti[32][33];
    const int bx = blockIdx.x * 32;   // e range
    const int by = blockIdx.y * 32;   // f range
    const int tx = threadIdx.x & 31, ty = threadIdx.x >> 5;
    for (int i = ty; i < 32; i += 8) {
        tr[i][tx] = wore[(bx + i) * E_DIM + by + tx];
        ti[i][tx] = woim[(bx + i) * E_DIM + by + tx];
    }
    __syncthreads();
    for (int i = ty; i < 32; i += 8) {
        wtre[(by + i) * E_DIM + bx + tx] = f2bf(tr[tx][i]);
        wtim[(by + i) * E_DIM + bx + tx] = f2bf(ti[tx][i]);
    }
}

// v planes [bh][t][64] -> v^T planes [bh][v][1024]
__global__ __launch_bounds__(256) void vtrans(
    const unsigned short* __restrict__ vrp, const unsigned short* __restrict__ vip,
    unsigned short* __restrict__ vrt, unsigned short* __restrict__ vit)
{
    __shared__ unsigned short tl[2][64][66];
    const int tid = threadIdx.x;
    const int t0 = blockIdx.x * 64;
    const int bh = blockIdx.y;
    #pragma unroll
    for (int pl = 0; pl < 2; ++pl) {
        const unsigned short* src = pl ? vip : vrp;
        #pragma unroll
        for (int p = 0; p < 2; ++p) {
            const int row = p * 32 + (tid >> 3);
            const int col = (tid & 7) * 8;
            short8 d = *(const short8*)&src[((size_t)bh * S_DIM + t0 + row) * V_DIM + col];
            #pragma unroll
            for (int j = 0; j < 8; ++j) tl[pl][row][col + j] = (unsigned short)d[j];
        }
    }
    __syncthreads();
    #pragma unroll
    for (int pl = 0; pl < 2; ++pl) {
        unsigned short* dst = pl ? vit : vrt;
        #pragma unroll
        for (int p = 0; p < 2; ++p) {
            const int v = p * 32 + (tid >> 3);
            const int tc = (tid & 7) * 8;
            short8 d;
            #pragma unroll
            for (int j = 0; j < 8; ++j) d[j] = (short)tl[pl][tc + j][v];
            *(short8*)&dst[((size_t)bh * V_DIM + v) * S_DIM + t0 + tc] = d;
        }
    }
}

// ---------------- complex bf16 MFMA GEMM: C = A * B^T ----------------
// MODE 0 (frozen since round 5: ~155 us, MfmaUtil 52%, 0 bank conflicts):
// block 128x128, 4 waves (2x2), wave tile 64x64, 16x16x32 frags, BK=32,
// T3-min double-buffer, chunk-XOR swizzle. qscale folded into q epilogue.
// MODE 1 (BM=64, 3 blocks/CU; round-9 measured neutral vs 128-tile).
template<int MODE>
__global__ __launch_bounds__(256, MODE ? 3 : 2) void cgemm(
    const unsigned short* __restrict__ Are, const unsigned short* __restrict__ Aim,
    const unsigned short* __restrict__ Bre, const unsigned short* __restrict__ Bim,
    unsigned short* __restrict__ qrp, unsigned short* __restrict__ qip,
    unsigned short* __restrict__ krp, unsigned short* __restrict__ kip,
    unsigned short* __restrict__ vrp, unsigned short* __restrict__ vip,
    const float* __restrict__ xre, const float* __restrict__ xim,
    float* __restrict__ out)
{
    constexpr int BM  = MODE ? 64 : 128;       // block M rows
    constexpr int IM  = MODE ? 2 : 4;          // wave m-frag count
    constexpr int ASZ = BM * 32;               // A plane elems per slice buffer
    constexpr int BUF = 2 * ASZ + 8192;        // elems per slice buffer (A*2 + B*2)
    __shared__ __align__(16) unsigned short lds[2 * BUF];
    const int tid  = threadIdx.x;
    const int wave = tid >> 6;
    const int lane = tid & 63;
    const int r0 = blockIdx.x * BM;
    const int j0 = blockIdx.y * 128;
    const int wm = (wave >> 1) * (MODE ? 32 : 64);   // m part
    const int wn = (wave & 1) * 64;                  // n half

    f32x4 accre[IM][4], accim[IM][4];
    #pragma unroll
    for (int i = 0; i < IM; ++i)
        #pragma unroll
        for (int j = 0; j < 4; ++j) {
            accre[i][j] = (f32x4){0.f, 0.f, 0.f, 0.f};
            accim[i][j] = (f32x4){0.f, 0.f, 0.f, 0.f};
        }

    const int sr   = tid >> 2;
    const int sc   = (tid & 3) * 8;                          // physical chunk (shorts)
    const int scol = ((tid & 3) ^ ((tid >> 3) & 3)) * 8;     // pre-swizzled source col

    const int fr = lane & 15;                                // frag m/n index
    const int xc = ((lane >> 4) ^ ((lane >> 1) & 3)) * 8;    // swizzled k-chunk on read

    #define STAGE(sl, bb) { \
        const int kg = (sl) * 32; \
        unsigned short* b_ = &lds[(bb) * BUF]; \
        const size_t ga0 = (size_t)(r0 + sr) * E_DIM + kg + scol; \
        const size_t gb0 = (size_t)(j0 + sr) * E_DIM + kg + scol; \
        const size_t gb1 = (size_t)(j0 + 64 + sr) * E_DIM + kg + scol; \
        async16(Are + ga0, b_ + sr * 32 + sc); \
        async16(Aim + ga0, b_ + ASZ + sr * 32 + sc); \
        if (MODE == 0) { \
            const size_t ga1 = (size_t)(r0 + 64 + sr) * E_DIM + kg + scol; \
            async16(Are + ga1, b_ + (64 + sr) * 32 + sc); \
            async16(Aim + ga1, b_ + ASZ + (64 + sr) * 32 + sc); \
        } \
        async16(Bre + gb0, b_ + 2 * ASZ + sr * 32 + sc); \
        async16(Bre + gb1, b_ + 2 * ASZ + (64 + sr) * 32 + sc); \
        async16(Bim + gb0, b_ + 2 * ASZ + 4096 + sr * 32 + sc); \
        async16(Bim + gb1, b_ + 2 * ASZ + 4096 + (64 + sr) * 32 + sc); }

    STAGE(0, 0)
    asm volatile("s_waitcnt vmcnt(0)" ::: "memory");
    __builtin_amdgcn_s_barrier();

    #pragma unroll 1
    for (int s = 0; s < 32; ++s) {
        if (s < 31) STAGE(s + 1, (s + 1) & 1)

        const unsigned short* buf = &lds[(s & 1) * BUF];
        short8 ar[IM], ai[IM];
        #pragma unroll
        for (int im = 0; im < IM; ++im) {
            const int ro = (wm + im * 16 + fr) * 32 + xc;
            ar[im] = *(const short8*)&buf[ro];
            ai[im] = *(const short8*)&buf[ASZ + ro];
        }
        #pragma unroll
        for (int jn = 0; jn < 4; ++jn) {
            const int ro = (wn + jn * 16 + fr) * 32 + xc;
            const short8 br = *(const short8*)&buf[2 * ASZ + ro];
            const short8 bi = *(const short8*)&buf[2 * ASZ + 4096 + ro];
            int4v t = *(int4v*)&bi;
            t = t ^ (int)0x80008000;       // bin = -bi (transient)
            const short8 bin = *(short8*)&t;
            #pragma unroll
            for (int im = 0; im < IM; ++im) {
                accre[im][jn] = __builtin_amdgcn_mfma_f32_16x16x32_bf16(ar[im], br,  accre[im][jn], 0, 0, 0);
                accre[im][jn] = __builtin_amdgcn_mfma_f32_16x16x32_bf16(ai[im], bin, accre[im][jn], 0, 0, 0);
                accim[im][jn] = __builtin_amdgcn_mfma_f32_16x16x32_bf16(ar[im], bi,  accim[im][jn], 0, 0, 0);
                accim[im][jn] = __builtin_amdgcn_mfma_f32_16x16x32_bf16(ai[im], br,  accim[im][jn], 0, 0, 0);
            }
        }

        if (s < 31) {
            asm volatile("s_waitcnt vmcnt(0)" ::: "memory");
            __builtin_amdgcn_s_barrier();
        }
    }
    #undef STAGE

    // epilogue: D row = (lane>>4)*4+reg, col = lane&15  [measured m89/m91]
    const float qscale = 0.088388347648318447f;  // 1/sqrt(128), folded into q planes
    #pragma unroll
    for (int im = 0; im < IM; ++im) {
        #pragma unroll
        for (int reg = 0; reg < 4; ++reg) {
            const int r = r0 + wm + im * 16 + (lane >> 4) * 4 + reg;
            #pragma unroll
            for (int jn = 0; jn < 4; ++jn) {
                const int j = j0 + wn + jn * 16 + fr;
                const float vr = accre[im][jn][reg];
                const float vi = accim[im][jn][reg];
                if (MODE == 0) {
                    const int s = r >> 2, b = r & 3;   // r = s*B + b
                    if (j < 2048) {
                        const int h = j >> 7, m = j & 127;
                        const size_t off = ((size_t)(b * H_DIM + h) * S_DIM + s) * M_DIM + m;
                        qrp[off] = f2bf(vr * qscale); qip[off] = f2bf(vi * qscale);
                    } else if (j < 4096) {
                        const int jl = j - 2048, h = jl >> 7, m = jl & 127;
                        const size_t off = ((size_t)(b * H_DIM + h) * S_DIM + s) * M_DIM + m;
                        krp[off] = f2bf(vr); kip[off] = f2bf(vi);
                    } else {
                        const int jl = j - 4096, h = jl >> 6, vv = jl & 63;
                        const size_t off = ((size_t)(b * H_DIM + h) * S_DIM + s) * V_DIM + vv;
                        vrp[off] = f2bf(vr); vip[off] = f2bf(vi);
                    }
                } else {
                    const int idx = r * E_DIM + j;
                    out[idx] = vr + xre[idx];
                    out[S_DIM * B_DIM * E_DIM + idx] = vi + xim[idx];
                }
            }
        }
    }
}

// ---------------- K2: MFMA flash attention, KVBLK=32, 3 blocks/CU ----------------
// Round-10: occupancy experiment. LDS diet via chunk-XOR swizzles (the exact
// pattern verified conflict-free in cgemm; all read/write bank mappings here
// are <=2-way = free per m136): Ks [2buf][2pl][32][128] 32KB + Vs
// [2buf][2pl][64][32] 16KB + Ps [4][16][32] 4KB = 53,248 B -> 3 blocks/CU
// (12 waves, +50% TLP vs round-7's 2 blocks). K/V double-buffered ->
// SINGLE barrier per tile (commit(t)->buf[t&1]: its previous readers ran
// before the prior iteration's barrier; commit->read within the iteration is
// the one barrier). Per-t-work MFMA/LDS/barrier counts identical to round-7:
// the isolated delta is occupancy + pipelining grain. Q loads one-shot direct
// from global (drops the Q-stage pass + barrier). Wave-uniform `continue`
// skips fully-masked tiles. Kept: XCD bh remap, folded qscale, T13 defer-max,
// setprio. launch_bounds(256,3): VGPR cap 170, est. peak ~130 (no spill).
__global__ __launch_bounds__(256, 3) void attn_mfma(
    const unsigned short* __restrict__ qr, const unsigned short* __restrict__ qi,
    const unsigned short* __restrict__ kr, const unsigned short* __restrict__ ki,
    const unsigned short* __restrict__ vrt, const unsigned short* __restrict__ vit,
    unsigned short* __restrict__ updre, unsigned short* __restrict__ updim)
{
    __shared__ __align__(16) unsigned short Ks[2][2][32][128]; // [buf][pl][t][m], chunk^(t&7)
    __shared__ __align__(16) unsigned short Vs[2][2][64][32];  // [buf][pl][v][t], chunk^((v>>1)&3)
    __shared__ __align__(16) unsigned short Ps[4][16][32];     // [wave][q][t],   chunk^((q>>1)&3)

    const int tid  = threadIdx.x;
    const int wave = tid >> 6;
    const int lane = tid & 63;

    // XCD-aware remap (round-7 verified): n%8 ~ XCD
    const int n  = blockIdx.x + 16 * blockIdx.y;
    const int m_ = n >> 3;
    const int bh = (n & 7) + 8 * (m_ >> 4);
    const int qt = 15 - (m_ & 15);

    const int q0 = qt * 64;
    const size_t base_qk = (size_t)bh * S_DIM * M_DIM;
    const size_t base_v  = (size_t)bh * V_DIM * S_DIM;

    const int fr = lane & 15;        // q col (QK/PV); A-frag row index
    const int fg = lane >> 4;        // quad 0..3
    const int fk = fg * 8;           // frag k offset (bf16)

    // staging coords (256 threads)
    const int krow = tid >> 4;       // 0..15 -> rows krow, krow+16
    const int kch  = tid & 15;       // K m-chunk 0..15
    const int vrow = tid >> 2;       // 0..63
    const int vch  = tid & 3;        // V t-chunk 0..3

    // ---- Q frags direct from global (one-shot; 16 distinct rows per wave) ----
    short8 Bqr[4], Bqi[4];
    {
        const size_t qo = base_qk + (size_t)(q0 + wave * 16 + fr) * M_DIM + fk;
        #pragma unroll
        for (int ks = 0; ks < 4; ++ks) {
            Bqr[ks] = *(const short8*)&qr[qo + ks * 32];
            Bqi[ks] = *(const short8*)&qi[qo + ks * 32];
        }
    }

    f32x4 Ore[4], Oim[4];   // O^T[v = vt*16+fg*4+reg][q = fr]
    #pragma unroll
    for (int vt = 0; vt < 4; ++vt) {
        Ore[vt] = (f32x4){0.f, 0.f, 0.f, 0.f};
        Oim[vt] = (f32x4){0.f, 0.f, 0.f, 0.f};
    }
    float mrun = -INFINITY, lrun = 0.f;
    const int qglob = q0 + wave * 16 + fr;      // this lane's q
    const int qcap  = q0 + wave * 16 + 15;      // wave-uniform max q

    // ---- prefetch tile t0=0 into registers ----
    short8 pk[2][2], pv[2];
    #pragma unroll
    for (int pl = 0; pl < 2; ++pl) {
        const unsigned short* src = pl ? ki : kr;
        #pragma unroll
        for (int p = 0; p < 2; ++p)
            pk[pl][p] = *(const short8*)&src[base_qk + (size_t)(p * 16 + krow) * M_DIM + kch * 8];
        const unsigned short* vsrc = pl ? vit : vrt;
        pv[pl] = *(const short8*)&vsrc[base_v + (size_t)vrow * S_DIM + vch * 8];
    }

    const int tmax = q0 + 32;   // last tile start (covers q0+32..q0+63)
    for (int t0 = 0; t0 <= tmax; t0 += 32) {
        const int bf = (t0 >> 5) & 1;
        // ---- commit prefetched tile into buf bf (prev readers >=1 barrier back) ----
        #pragma unroll
        for (int pl = 0; pl < 2; ++pl) {
            #pragma unroll
            for (int p = 0; p < 2; ++p) {
                const int row = p * 16 + krow;
                *(short8*)&Ks[bf][pl][row][(kch ^ (row & 7)) << 3] = pk[pl][p];
            }
            *(short8*)&Vs[bf][pl][vrow][(vch ^ ((vrow >> 1) & 3)) << 3] = pv[pl];
        }
        // ---- issue next tile's global loads ----
        if (t0 < tmax) {
            const int tn = t0 + 32;
            #pragma unroll
            for (int pl = 0; pl < 2; ++pl) {
                const unsigned short* src = pl ? ki : kr;
                #pragma unroll
                for (int p = 0; p < 2; ++p)
                    pk[pl][p] = *(const short8*)&src[base_qk + (size_t)(tn + p * 16 + krow) * M_DIM + kch * 8];
                const unsigned short* vsrc = pl ? vit : vrt;
                pv[pl] = *(const short8*)&vsrc[base_v + (size_t)vrow * S_DIM + tn + vch * 8];
            }
        }
        __syncthreads();   // the single barrier: commit visible to all waves

        // ---- wave-uniform skip of fully-masked tile ----
        if (t0 > qcap) continue;

        // ---- S^T = K Q^T (complex): A = K frags (swizzled LDS) ----
        f32x4 Sre[2], Sim[2];   // t = tt*16 + fg*4 + reg, q = fr
        __builtin_amdgcn_s_setprio(1);
        #pragma unroll
        for (int tt = 0; tt < 2; ++tt) {
            Sre[tt] = (f32x4){0.f, 0.f, 0.f, 0.f};
            Sim[tt] = (f32x4){0.f, 0.f, 0.f, 0.f};
            const int trow = tt * 16 + fr;
            const int sw = trow & 7;
            #pragma unroll
            for (int ks = 0; ks < 4; ++ks) {
                const int off = ((ks * 4 + fg) ^ sw) << 3;
                const short8 Akr = *(const short8*)&Ks[bf][0][trow][off];
                const short8 Aki = *(const short8*)&Ks[bf][1][trow][off];
                int4v t = *(int4v*)&Aki;
                t = t ^ (int)0x80008000;       // -Ki (transient)
                const short8 Akin = *(short8*)&t;
                Sre[tt] = __builtin_amdgcn_mfma_f32_16x16x32_bf16(Akr,  Bqr[ks], Sre[tt], 0, 0, 0);
                Sre[tt] = __builtin_amdgcn_mfma_f32_16x16x32_bf16(Akin, Bqi[ks], Sre[tt], 0, 0, 0);
                Sim[tt] = __builtin_amdgcn_mfma_f32_16x16x32_bf16(Akr,  Bqi[ks], Sim[tt], 0, 0, 0);
                Sim[tt] = __builtin_amdgcn_mfma_f32_16x16x32_bf16(Aki,  Bqr[ks], Sim[tt], 0, 0, 0);
            }
        }
        __builtin_amdgcn_s_setprio(0);

        // ---- amplitude + causal mask (overwrites Sre); in-lane + 2 quad shfls ----
        float rowmax = -INFINITY;
        #pragma unroll
        for (int tt = 0; tt < 2; ++tt) {
            #pragma unroll
            for (int r = 0; r < 4; ++r) {
                const int tg = t0 + tt * 16 + fg * 4 + r;
                const float re = Sre[tt][r], im = Sim[tt][r];
                const float a = sqrtf(re * re + im * im);   // scale pre-folded into q
                const float av = (tg > qglob) ? -INFINITY : a;
                Sre[tt][r] = av;
                rowmax = fmaxf(rowmax, av);
            }
        }
        rowmax = fmaxf(rowmax, __shfl_xor(rowmax, 16));
        rowmax = fmaxf(rowmax, __shfl_xor(rowmax, 32));

        // T13 defer-max: rescale only when the max grows materially
        if (!__all(rowmax - mrun <= 8.0f)) {
            const float nm = fmaxf(mrun, rowmax);
            const float alpha = __expf(mrun - nm);
            mrun = nm;
            lrun *= alpha;
            #pragma unroll
            for (int vt = 0; vt < 4; ++vt)
                #pragma unroll
                for (int r = 0; r < 4; ++r) { Ore[vt][r] *= alpha; Oim[vt][r] *= alpha; }
        }

        float psum = 0.f;
        const int psw = (fr >> 1) & 3;   // Ps chunk swizzle key for this row
        #pragma unroll
        for (int tt = 0; tt < 2; ++tt) {
            const float p0 = __expf(Sre[tt][0] - mrun);
            const float p1 = __expf(Sre[tt][1] - mrun);
            const float p2 = __expf(Sre[tt][2] - mrun);
            const float p3 = __expf(Sre[tt][3] - mrun);
            psum += p0 + p1 + p2 + p3;
            ushort4 pw;
            pw.x = f2bf(p0); pw.y = f2bf(p1); pw.z = f2bf(p2); pw.w = f2bf(p3);
            // logical col = tt*16 + fg*4 -> chunk c = tt*2 + (fg>>1), sub = (fg&1)*4
            const int poff = (((tt * 2 + (fg >> 1)) ^ psw) << 3) + (fg & 1) * 4;
            *(ushort4*)&Ps[wave][fr][poff] = pw;
        }
        psum += __shfl_xor(psum, 16);
        psum += __shfl_xor(psum, 32);
        lrun += psum;

        // ---- O^T += V^T P^T : A = V^T frags (swizzled LDS), B = P frag ----
        const short8 Bp = *(const short8*)&Ps[wave][fr][(fg ^ psw) << 3];
        __builtin_amdgcn_s_setprio(1);
        #pragma unroll
        for (int vt = 0; vt < 4; ++vt) {
            const int vr2 = vt * 16 + fr;
            const int voff = (fg ^ ((vr2 >> 1) & 3)) << 3;
            const short8 Ar = *(const short8*)&Vs[bf][0][vr2][voff];
            const short8 Ai = *(const short8*)&Vs[bf][1][vr2][voff];
            Ore[vt] = __builtin_amdgcn_mfma_f32_16x16x32_bf16(Ar, Bp, Ore[vt], 0, 0, 0);
            Oim[vt] = __builtin_amdgcn_mfma_f32_16x16x32_bf16(Ai, Bp, Oim[vt], 0, 0, 0);
        }
        __builtin_amdgcn_s_setprio(0);
    }

    // ---- epilogue: lane owns q = qglob; v = vt*16 + fg*4 + reg ----
    const int b = bh >> 4, h = bh & 15;
    const float inv = 1.0f / lrun;
    const size_t base = ((size_t)(qglob * B_DIM + b)) * E_DIM + h * V_DIM;
    #pragma unroll
    for (int vt = 0; vt < 4; ++vt) {
        ushort4 pr, pi;
        pr.x = f2bf(Ore[vt][0] * inv); pr.y = f2bf(Ore[vt][1] * inv);
        pr.z = f2bf(Ore[vt][2] * inv); pr.w = f2bf(Ore[vt][3] * inv);
        pi.x = f2bf(Oim[vt][0] * inv); pi.y = f2bf(Oim[vt][1] * inv);
        pi.z = f2bf(Oim[vt][2] * inv); pi.w = f2bf(Oim[vt][3] * inv);
        *(ushort4*)&updre[base + vt * 16 + fg * 4] = pr;
        *(ushort4*)&updim[base + vt * 16 + fg * 4] = pi;
    }
}

extern "C" void kernel_launch(void* const* d_in, const int* in_sizes, int n_in,
                              void* d_out, int out_size, void* d_ws, size_t ws_size,
                              hipStream_t stream) {
    const float* xre  = (const float*)d_in[0];
    const float* xim  = (const float*)d_in[1];
    const float* wqre = (const float*)d_in[2];
    const float* wqim = (const float*)d_in[3];
    const float* wkre = (const float*)d_in[4];
    const float* wkim = (const float*)d_in[5];
    const float* wvre = (const float*)d_in[6];
    const float* wvim = (const float*)d_in[7];
    const float* wore = (const float*)d_in[8];
    const float* woim = (const float*)d_in[9];
    float* out = (float*)d_out;

    // workspace layout (~160 MB)
    char* p = (char*)d_ws;
    const size_t QK = (size_t)B_DIM * H_DIM * S_DIM * M_DIM;   // 8.39M
    const size_t VS = (size_t)B_DIM * H_DIM * S_DIM * V_DIM;   // 4.19M
    const size_t SBE = (size_t)S_DIM * B_DIM * E_DIM;          // 4.19M
    unsigned short* qrw = (unsigned short*)p;  p += QK * 2;
    unsigned short* qiw = (unsigned short*)p;  p += QK * 2;
    unsigned short* krw = (unsigned short*)p;  p += QK * 2;
    unsigned short* kiw = (unsigned short*)p;  p += QK * 2;
    unsigned short* vrw = (unsigned short*)p;  p += VS * 2;
    unsigned short* viw = (unsigned short*)p;  p += VS * 2;
    unsigned short* vrt = (unsigned short*)p;  p += VS * 2;
    unsigned short* vit = (unsigned short*)p;  p += VS * 2;
    unsigned short* updre = (unsigned short*)p; p += SBE * 2;
    unsigned short* updim = (unsigned short*)p; p += SBE * 2;
    unsigned short* xbre  = (unsigned short*)p; p += SBE * 2;
    unsigned short* xbim  = (unsigned short*)p; p += SBE * 2;
    unsigned short* wbre  = (unsigned short*)p; p += (size_t)5120 * E_DIM * 2;
    unsigned short* wbim  = (unsigned short*)p; p += (size_t)5120 * E_DIM * 2;
    unsigned short* wtre  = (unsigned short*)p; p += (size_t)E_DIM * E_DIM * 2;
    unsigned short* wtim  = (unsigned short*)p; p += (size_t)E_DIM * E_DIM * 2;

    // bf16 conversion (single fused launch) + wo transpose
    convert_all<<<9216, 256, 0, stream>>>(xre, xim, wqre, wqim, wkre, wkim, wvre, wvim,
                                          xbre, xbim, wbre, wbim);
    transpose_wo<<<dim3(32, 32), 256, 0, stream>>>(wore, woim, wtre, wtim);

    // QKV projection (bf16 MFMA 16x16x32, 64x64 wave tile, T3-min dbuf)
    cgemm<0><<<dim3(32, 40), 256, 0, stream>>>(xbre, xbim, wbre, wbim,
                                               qrw, qiw, krw, kiw, vrw, viw,
                                               nullptr, nullptr, nullptr);
    // V -> V^T planes
    vtrans<<<dim3(16, 64), 256, 0, stream>>>(vrw, viw, vrt, vit);
    // MFMA flash attention (KVBLK=32, double-buffered, 1 barrier/tile, 3 blocks/CU)
    attn_mfma<<<dim3(16, 64), 256, 0, stream>>>(qrw, qiw, krw, kiw, vrt, vit, updre, updim);
    // output projection + residual (BM=64 tile -> 512 blocks, 3 blocks/CU)
    cgemm<1><<<dim3(64, 8), 256, 0, stream>>>(updre, updim, wtre, wtim,
                                              nullptr, nullptr, nullptr, nullptr, nullptr, nullptr,
                                              xre, xim, out);
}